// Round 5
// baseline (401.987 us; speedup 1.0000x reference)
//
#include <hip/hip_runtime.h>

// apply_cdna_kernels: out[n,b,c,h,w] = sum_{kh,kw} images[b,h+kh-2,w+kw-2,c] * kernels[b,kh,kw,n]
// images: [64,128,128,3] f32   kernels: [64,5,5,10] f32   out: [10,64,3,128,128] f32
//
// R6 = R5 with the nontemporal-store compile fix (ext_vector_type instead of
// HIP_vector_type — builtin requires native vector types).
// R5 theory: R4 was latency-bound (512 blocks = 2/CU, Occupancy 7%, VALUBusy 6%).
//  - TH=8 tile -> 1024 blocks = 4 blocks/CU = 16 waves/CU, LDS 19KB
//  - thread = 1h x 4w x 3c, n processed in PAIRS (two SGPR weight sets) ->
//    LDS reads halved vs per-n: 5 pairs x 5 rows x 6 ds_read_b128
//  - live set ~80 VGPR (24 acc + 24 px + addr) < 128 cap -> no spill
//  - nontemporal stores: output never re-read; kills write-allocate RFO
//    (R4: FETCH 74.5MB ~= 19 ideal + 0.5*output -> RMW suspicion) + L2 thrash
// Floors: write 20us || VALU 10us || LDS 9us -> expect ~25-35us kernel.

#define B_  64
#define H_  128
#define W_  128
#define C_  3
#define N_  10
#define KH_ 5
#define KW_ 5
#define TH_ 8                  // tile height (full W width)
#define LDS_ROWS (TH_ + 4)     // 12 rows incl. halo
#define ROW_F ((W_ + 4) * C_)  // 132 px * 3 = 396 floats per row (1584B)
#define ROW_VALID (W_ * C_)    // 384 valid floats per global image row
#define HW_ (H_ * W_)          // 16384

typedef float f32x4 __attribute__((ext_vector_type(4)));

__global__ __launch_bounds__(256, 4) void cdna_apply_kernel(
    const float* __restrict__ images,
    const float* __restrict__ kernels,
    float* __restrict__ out)
{
    __shared__ __align__(16) float s_img[LDS_ROWS * ROW_F];

    const int tid = threadIdx.x;
    const int ht  = blockIdx.x;   // 16
    const int b   = blockIdx.y;   // 64
    const int y0  = ht * TH_;

    // ---- stage image tile (12 rows x 99 float4; zero-padded halo), once ----
    const float* __restrict__ ib = images + (long)b * (H_ * W_ * C_);
    for (int i = tid; i < LDS_ROWS * (ROW_F / 4); i += 256) {
        const int r  = i / (ROW_F / 4);        // LDS row 0..11
        const int q  = i - r * (ROW_F / 4);    // float4 index in row, 0..98
        const int y  = y0 + r - 2;
        float v0 = 0.f, v1 = 0.f, v2 = 0.f, v3 = 0.f;
        if ((unsigned)y < (unsigned)H_) {
            const float* grow = ib + (long)y * ROW_VALID;
            const int f0 = q * 4 - 6;          // offset into 384-float global row (even)
            if (f0 >= 0 && f0 <= ROW_VALID - 4) {
                const float2 a  = *(const float2*)(grow + f0);
                const float2 c2 = *(const float2*)(grow + f0 + 2);
                v0 = a.x; v1 = a.y; v2 = c2.x; v3 = c2.y;
            } else {
                if (f0 + 0 >= 0 && f0 + 0 < ROW_VALID) v0 = grow[f0 + 0];
                if (f0 + 1 >= 0 && f0 + 1 < ROW_VALID) v1 = grow[f0 + 1];
                if (f0 + 2 >= 0 && f0 + 2 < ROW_VALID) v2 = grow[f0 + 2];
                if (f0 + 3 >= 0 && f0 + 3 < ROW_VALID) v3 = grow[f0 + 3];
            }
        }
        *(float4*)(&s_img[r * ROW_F + q * 4]) = make_float4(v0, v1, v2, v3);
    }
    __syncthreads();

    const int tx = tid & 31;      // 4w column group: cols 4tx..4tx+3
    const int ty = tid >> 5;      // 0..7 output row within tile

    const float* __restrict__ kb = kernels + (long)b * (KH_ * KW_ * N_);
    const int h = y0 + ty;
    float* ob0 = out + (long)b * (C_ * HW_) + (long)h * W_ + tx * 4;
    const long nstride = (long)B_ * C_ * HW_;

    #pragma unroll 1
    for (int np = 0; np < N_ / 2; ++np) {
        const int n0 = 2 * np;
        // 2 x 25 block-uniform weights -> SGPRs (scalar-cache hit after np=0)
        float wt0[KH_ * KW_], wt1[KH_ * KW_];
        #pragma unroll
        for (int k = 0; k < KH_ * KW_; ++k) {
            wt0[k] = kb[k * N_ + n0];
            wt1[k] = kb[k * N_ + n0 + 1];
        }

        float a0[12], a1[12];                  // [c*4 + w] for n0, n0+1
        #pragma unroll
        for (int i = 0; i < 12; ++i) { a0[i] = 0.f; a1[i] = 0.f; }

        #pragma unroll
        for (int r = 0; r < KH_; ++r) {
            const float4* rp = (const float4*)&s_img[(ty + r) * ROW_F + tx * 12];
            float px[24];                      // pixels x=4tx-2..4tx+5, 3 c each
            #pragma unroll
            for (int j = 0; j < 6; ++j) {      // 6x ds_read_b128, conflict-free
                const float4 t = rp[j];
                px[j * 4 + 0] = t.x; px[j * 4 + 1] = t.y;
                px[j * 4 + 2] = t.z; px[j * 4 + 3] = t.w;
            }
            #pragma unroll
            for (int kw = 0; kw < KW_; ++kw) {
                const float w0 = wt0[r * KW_ + kw];
                const float w1 = wt1[r * KW_ + kw];
                #pragma unroll
                for (int w = 0; w < 4; ++w)
                    #pragma unroll
                    for (int c = 0; c < C_; ++c) {
                        const float p = px[(kw + w) * 3 + c];
                        a0[c * 4 + w] = fmaf(p, w0, a0[c * 4 + w]);
                        a1[c * 4 + w] = fmaf(p, w1, a1[c * 4 + w]);
                    }
            }
        }

        // nontemporal dwordx4 stores: contiguous 512B per (n,c,h) row across lanes
        float* p0 = ob0 + (long)n0 * nstride;
        float* p1 = p0 + nstride;
        #pragma unroll
        for (int c = 0; c < C_; ++c) {
            f32x4 v0 = { a0[c*4+0], a0[c*4+1], a0[c*4+2], a0[c*4+3] };
            f32x4 v1 = { a1[c*4+0], a1[c*4+1], a1[c*4+2], a1[c*4+3] };
            __builtin_nontemporal_store(v0, (f32x4*)(p0 + (long)c * HW_));
            __builtin_nontemporal_store(v1, (f32x4*)(p1 + (long)c * HW_));
        }
    }
}

extern "C" void kernel_launch(void* const* d_in, const int* in_sizes, int n_in,
                              void* d_out, int out_size, void* d_ws, size_t ws_size,
                              hipStream_t stream) {
    const float* images  = (const float*)d_in[0];
    const float* kernels = (const float*)d_in[1];
    float* out = (float*)d_out;

    dim3 grid(H_ / TH_, B_);   // 16 x 64 = 1024 blocks, 4 per CU
    cdna_apply_kernel<<<grid, 256, 0, stream>>>(images, kernels, out);
}

// Round 6
// 384.835 us; speedup vs baseline: 1.0446x; 1.0446x over previous
//
#include <hip/hip_runtime.h>

// apply_cdna_kernels: out[n,b,c,h,w] = sum_{kh,kw} images[b,h+kh-2,w+kw-2,c] * kernels[b,kh,kw,n]
// images: [64,128,128,3] f32   kernels: [64,5,5,10] f32   out: [10,64,3,128,128] f32
//
// R7 = R6 minus the spill. Session-long lesson: allocator VGPR budget is
// empirically 256/launch_bounds_arg (arg4->64 [R1,R6], arg3->84 [R3],
// arg2->128 [R4]); it spills rather than relax. R6's live set (~100: 24 acc +
// 24 px + 50 VGPR-resident weights) blew its 64-reg budget -> 764MB scratch
// FETCH, 448MB WRITE, VALUBusy 3.8%.
//  - __launch_bounds__(256,2): 128-VGPR budget (R4 proved no-spill there)
//  - weights forced to SGPRs via readfirstlane (block-uniform; ~75 < 102 SGPR)
//    -> vector live set ~60-80 VGPR, spill structurally impossible
//  - occupancy: LDS 19KB (8/CU), VGPR<=128 (4 waves/SIMD) -> 4 blocks/CU
//    resident with grid 1024 = 16 waves/CU
//  - keep: all-N-per-block reuse, n-pairs (LDS reads halved), ds_read_b128,
//    nontemporal dwordx4 stores (kill write-allocate RFO seen in R4)
// Floors: write 20us || VALU 10us || LDS 9us -> expect ~30-45us kernel.

#define B_  64
#define H_  128
#define W_  128
#define C_  3
#define N_  10
#define KH_ 5
#define KW_ 5
#define TH_ 8                  // tile height (full W width)
#define LDS_ROWS (TH_ + 4)     // 12 rows incl. halo
#define ROW_F ((W_ + 4) * C_)  // 132 px * 3 = 396 floats per row (1584B)
#define ROW_VALID (W_ * C_)    // 384 valid floats per global image row
#define HW_ (H_ * W_)          // 16384

typedef float f32x4 __attribute__((ext_vector_type(4)));

// force a block-uniform float into an SGPR
__device__ __forceinline__ float uni(float x) {
    return __int_as_float(__builtin_amdgcn_readfirstlane(__float_as_int(x)));
}

__global__ __launch_bounds__(256, 2) void cdna_apply_kernel(
    const float* __restrict__ images,
    const float* __restrict__ kernels,
    float* __restrict__ out)
{
    __shared__ __align__(16) float s_img[LDS_ROWS * ROW_F];

    const int tid = threadIdx.x;
    const int ht  = blockIdx.x;   // 16
    const int b   = blockIdx.y;   // 64
    const int y0  = ht * TH_;

    // ---- stage image tile (12 rows x 99 float4; zero-padded halo), once ----
    const float* __restrict__ ib = images + (long)b * (H_ * W_ * C_);
    for (int i = tid; i < LDS_ROWS * (ROW_F / 4); i += 256) {
        const int r  = i / (ROW_F / 4);        // LDS row 0..11
        const int q  = i - r * (ROW_F / 4);    // float4 index in row, 0..98
        const int y  = y0 + r - 2;
        float v0 = 0.f, v1 = 0.f, v2 = 0.f, v3 = 0.f;
        if ((unsigned)y < (unsigned)H_) {
            const float* grow = ib + (long)y * ROW_VALID;
            const int f0 = q * 4 - 6;          // offset into 384-float global row (even)
            if (f0 >= 0 && f0 <= ROW_VALID - 4) {
                const float2 a  = *(const float2*)(grow + f0);
                const float2 c2 = *(const float2*)(grow + f0 + 2);
                v0 = a.x; v1 = a.y; v2 = c2.x; v3 = c2.y;
            } else {
                if (f0 + 0 >= 0 && f0 + 0 < ROW_VALID) v0 = grow[f0 + 0];
                if (f0 + 1 >= 0 && f0 + 1 < ROW_VALID) v1 = grow[f0 + 1];
                if (f0 + 2 >= 0 && f0 + 2 < ROW_VALID) v2 = grow[f0 + 2];
                if (f0 + 3 >= 0 && f0 + 3 < ROW_VALID) v3 = grow[f0 + 3];
            }
        }
        *(float4*)(&s_img[r * ROW_F + q * 4]) = make_float4(v0, v1, v2, v3);
    }
    __syncthreads();

    const int tx = tid & 31;      // 4w column group: cols 4tx..4tx+3
    const int ty = tid >> 5;      // 0..7 output row within tile

    const float* __restrict__ kb = kernels + (long)b * (KH_ * KW_ * N_);
    const int h = y0 + ty;
    float* ob0 = out + (long)b * (C_ * HW_) + (long)h * W_ + tx * 4;
    const long nstride = (long)B_ * C_ * HW_;

    #pragma unroll 1
    for (int np = 0; np < N_ / 2; ++np) {
        const int n0 = 2 * np;
        // 2 x 25 block-uniform weights -> forced into SGPRs (readfirstlane)
        float wt0[KH_ * KW_], wt1[KH_ * KW_];
        #pragma unroll
        for (int k = 0; k < KH_ * KW_; ++k) {
            wt0[k] = uni(kb[k * N_ + n0]);
            wt1[k] = uni(kb[k * N_ + n0 + 1]);
        }

        float a0[12], a1[12];                  // [c*4 + w] for n0, n0+1
        #pragma unroll
        for (int i = 0; i < 12; ++i) { a0[i] = 0.f; a1[i] = 0.f; }

        #pragma unroll
        for (int r = 0; r < KH_; ++r) {
            const float4* rp = (const float4*)&s_img[(ty + r) * ROW_F + tx * 12];
            float px[24];                      // pixels x=4tx-2..4tx+5, 3 c each
            #pragma unroll
            for (int j = 0; j < 6; ++j) {      // 6x ds_read_b128, conflict-free
                const float4 t = rp[j];
                px[j * 4 + 0] = t.x; px[j * 4 + 1] = t.y;
                px[j * 4 + 2] = t.z; px[j * 4 + 3] = t.w;
            }
            #pragma unroll
            for (int kw = 0; kw < KW_; ++kw) {
                const float w0 = wt0[r * KW_ + kw];
                const float w1 = wt1[r * KW_ + kw];
                #pragma unroll
                for (int w = 0; w < 4; ++w)
                    #pragma unroll
                    for (int c = 0; c < C_; ++c) {
                        const float p = px[(kw + w) * 3 + c];
                        a0[c * 4 + w] = fmaf(p, w0, a0[c * 4 + w]);
                        a1[c * 4 + w] = fmaf(p, w1, a1[c * 4 + w]);
                    }
            }
        }

        // nontemporal dwordx4 stores: contiguous 512B per (n,c,h) row across lanes
        float* p0 = ob0 + (long)n0 * nstride;
        float* p1 = p0 + nstride;
        #pragma unroll
        for (int c = 0; c < C_; ++c) {
            f32x4 v0 = { a0[c*4+0], a0[c*4+1], a0[c*4+2], a0[c*4+3] };
            f32x4 v1 = { a1[c*4+0], a1[c*4+1], a1[c*4+2], a1[c*4+3] };
            __builtin_nontemporal_store(v0, (f32x4*)(p0 + (long)c * HW_));
            __builtin_nontemporal_store(v1, (f32x4*)(p1 + (long)c * HW_));
        }
    }
}

extern "C" void kernel_launch(void* const* d_in, const int* in_sizes, int n_in,
                              void* d_out, int out_size, void* d_ws, size_t ws_size,
                              hipStream_t stream) {
    const float* images  = (const float*)d_in[0];
    const float* kernels = (const float*)d_in[1];
    float* out = (float*)d_out;

    dim3 grid(H_ / TH_, B_);   // 16 x 64 = 1024 blocks, 4 per CU
    cdna_apply_kernel<<<grid, 256, 0, stream>>>(images, kernels, out);
}

// Round 7
// 144.744 us; speedup vs baseline: 2.7772x; 2.6587x over previous
//
#include <hip/hip_runtime.h>

// apply_cdna_kernels: out[n,b,c,h,w] = sum_{kh,kw} images[b,h+kh-2,w+kw-2,c] * kernels[b,kh,kw,n]
// images: [64,128,128,3] f32   kernels: [64,5,5,10] f32   out: [10,64,3,128,128] f32
//
// R8 = R7 with PLAIN float4 stores. A/B evidence: nt-store rounds (R6/R7)
// pinned WRITE at ~450MB (3.6x the 126MB output) independent of register
// budget, while the plain-store round (R4) wrote 152MB. The nt builtin
// lowered to strided scalar dword stores -> partial-sector writes -> ~4x
// write amplification + sector-RMW reads (FETCH +390MB). Plain float4
// assignment emits global_store_dwordx4: 1KB contiguous per wave per (n,c),
// sector-complete.
// Kept from R7: launch_bounds(256,2) = 128-VGPR budget (spill-free),
// readfirstlane weights -> SGPRs, n-pairs (LDS reads halved), TH=8 tile,
// 1024 blocks = 4/CU = 16 waves/CU.
// Floors: write 20us || VALU 10us || LDS 9us -> expect ~30-50us kernel.

#define B_  64
#define H_  128
#define W_  128
#define C_  3
#define N_  10
#define KH_ 5
#define KW_ 5
#define TH_ 8                  // tile height (full W width)
#define LDS_ROWS (TH_ + 4)     // 12 rows incl. halo
#define ROW_F ((W_ + 4) * C_)  // 132 px * 3 = 396 floats per row (1584B)
#define ROW_VALID (W_ * C_)    // 384 valid floats per global image row
#define HW_ (H_ * W_)          // 16384

// force a block-uniform float into an SGPR
__device__ __forceinline__ float uni(float x) {
    return __int_as_float(__builtin_amdgcn_readfirstlane(__float_as_int(x)));
}

__global__ __launch_bounds__(256, 2) void cdna_apply_kernel(
    const float* __restrict__ images,
    const float* __restrict__ kernels,
    float* __restrict__ out)
{
    __shared__ __align__(16) float s_img[LDS_ROWS * ROW_F];

    const int tid = threadIdx.x;
    const int ht  = blockIdx.x;   // 16
    const int b   = blockIdx.y;   // 64
    const int y0  = ht * TH_;

    // ---- stage image tile (12 rows x 99 float4; zero-padded halo), once ----
    const float* __restrict__ ib = images + (long)b * (H_ * W_ * C_);
    for (int i = tid; i < LDS_ROWS * (ROW_F / 4); i += 256) {
        const int r  = i / (ROW_F / 4);        // LDS row 0..11
        const int q  = i - r * (ROW_F / 4);    // float4 index in row, 0..98
        const int y  = y0 + r - 2;
        float v0 = 0.f, v1 = 0.f, v2 = 0.f, v3 = 0.f;
        if ((unsigned)y < (unsigned)H_) {
            const float* grow = ib + (long)y * ROW_VALID;
            const int f0 = q * 4 - 6;          // offset into 384-float global row (even)
            if (f0 >= 0 && f0 <= ROW_VALID - 4) {
                const float2 a  = *(const float2*)(grow + f0);
                const float2 c2 = *(const float2*)(grow + f0 + 2);
                v0 = a.x; v1 = a.y; v2 = c2.x; v3 = c2.y;
            } else {
                if (f0 + 0 >= 0 && f0 + 0 < ROW_VALID) v0 = grow[f0 + 0];
                if (f0 + 1 >= 0 && f0 + 1 < ROW_VALID) v1 = grow[f0 + 1];
                if (f0 + 2 >= 0 && f0 + 2 < ROW_VALID) v2 = grow[f0 + 2];
                if (f0 + 3 >= 0 && f0 + 3 < ROW_VALID) v3 = grow[f0 + 3];
            }
        }
        *(float4*)(&s_img[r * ROW_F + q * 4]) = make_float4(v0, v1, v2, v3);
    }
    __syncthreads();

    const int tx = tid & 31;      // 4w column group: cols 4tx..4tx+3
    const int ty = tid >> 5;      // 0..7 output row within tile

    const float* __restrict__ kb = kernels + (long)b * (KH_ * KW_ * N_);
    const int h = y0 + ty;
    float* ob0 = out + (long)b * (C_ * HW_) + (long)h * W_ + tx * 4;
    const long nstride = (long)B_ * C_ * HW_;

    #pragma unroll 1
    for (int np = 0; np < N_ / 2; ++np) {
        const int n0 = 2 * np;
        // 2 x 25 block-uniform weights -> forced into SGPRs (readfirstlane)
        float wt0[KH_ * KW_], wt1[KH_ * KW_];
        #pragma unroll
        for (int k = 0; k < KH_ * KW_; ++k) {
            wt0[k] = uni(kb[k * N_ + n0]);
            wt1[k] = uni(kb[k * N_ + n0 + 1]);
        }

        float a0[12], a1[12];                  // [c*4 + w] for n0, n0+1
        #pragma unroll
        for (int i = 0; i < 12; ++i) { a0[i] = 0.f; a1[i] = 0.f; }

        #pragma unroll
        for (int r = 0; r < KH_; ++r) {
            const float4* rp = (const float4*)&s_img[(ty + r) * ROW_F + tx * 12];
            float px[24];                      // pixels x=4tx-2..4tx+5, 3 c each
            #pragma unroll
            for (int j = 0; j < 6; ++j) {      // 6x ds_read_b128, conflict-free
                const float4 t = rp[j];
                px[j * 4 + 0] = t.x; px[j * 4 + 1] = t.y;
                px[j * 4 + 2] = t.z; px[j * 4 + 3] = t.w;
            }
            #pragma unroll
            for (int kw = 0; kw < KW_; ++kw) {
                const float w0 = wt0[r * KW_ + kw];
                const float w1 = wt1[r * KW_ + kw];
                #pragma unroll
                for (int w = 0; w < 4; ++w)
                    #pragma unroll
                    for (int c = 0; c < C_; ++c) {
                        const float p = px[(kw + w) * 3 + c];
                        a0[c * 4 + w] = fmaf(p, w0, a0[c * 4 + w]);
                        a1[c * 4 + w] = fmaf(p, w1, a1[c * 4 + w]);
                    }
            }
        }

        // plain dwordx4 stores: 1KB contiguous per wave per (n,c) -> sector-complete
        float* p0 = ob0 + (long)n0 * nstride;
        float* p1 = p0 + nstride;
        #pragma unroll
        for (int c = 0; c < C_; ++c) {
            *(float4*)(p0 + (long)c * HW_) = make_float4(a0[c*4+0], a0[c*4+1], a0[c*4+2], a0[c*4+3]);
            *(float4*)(p1 + (long)c * HW_) = make_float4(a1[c*4+0], a1[c*4+1], a1[c*4+2], a1[c*4+3]);
        }
    }
}

extern "C" void kernel_launch(void* const* d_in, const int* in_sizes, int n_in,
                              void* d_out, int out_size, void* d_ws, size_t ws_size,
                              hipStream_t stream) {
    const float* images  = (const float*)d_in[0];
    const float* kernels = (const float*)d_in[1];
    float* out = (float*)d_out;

    dim3 grid(H_ / TH_, B_);   // 16 x 64 = 1024 blocks, 4 per CU
    cdna_apply_kernel<<<grid, 256, 0, stream>>>(images, kernels, out);
}